// Round 7
// baseline (808.595 us; speedup 1.0000x reference)
//
#include <hip/hip_runtime.h>
#include <math.h>

typedef unsigned short ushort_t;
typedef __attribute__((ext_vector_type(8))) short bf16x8;
typedef __attribute__((ext_vector_type(4))) float f32x4;

namespace {
constexpr int B = 8, S = 2048, H = 128, NH = 4, HS = 32;
constexpr float EPS = 1e-8f;
constexpr float SCALE = 0.17677669529663687f;   // 1/sqrt(32)
constexpr float LOG2E = 1.4426950408889634f;
constexpr float SCALEL = SCALE * LOG2E;         // folded into Wq/Wqb/bq/bqb
constexpr int QT = 16, KT = 64;
constexpr int KS = 2;                            // split-K factor
constexpr int SKT = S / KS / KT;                 // 16 k-tiles per split
constexpr int NE = B * S * H;                    // 2,097,152 elements per tensor
}

__device__ __forceinline__ ushort_t f2bf(float f) {
  unsigned u = __float_as_uint(f);
  unsigned r = (u + 0x7FFFu + ((u >> 16) & 1u)) >> 16;  // RNE
  return (ushort_t)r;
}

__device__ __forceinline__ f32x4 mfma16(bf16x8 a, bf16x8 b, f32x4 c) {
  return __builtin_amdgcn_mfma_f32_16x16x32_bf16(a, b, c, 0, 0, 0);
}

// ---------- Kernel 0a: mask-nonzero tile bits, 8-way column split for occupancy ----------
// bit kt of fm[b][qt] set if mask[b, qt*16:+16, kt*64:+64] has any nonzero (NaN-safe).
__global__ __launch_bounds__(256) void mflag_kernel(
    const float* __restrict__ mask, unsigned* __restrict__ fm)
{
  const int qt = blockIdx.x;
  const int b  = blockIdx.y;
  const int z  = blockIdx.z;           // 256-col chunk = 4 k-tiles
  const int t = threadIdx.x;
  const int lt = t >> 6;               // k-tile within chunk (0..3)
  const int lane = t & 63;
  // 64 lanes cover one 16x64 tile: rows (lane>>4)*4+rr, cols (lane&15)*4
  const float* mp = mask + ((long)b * S + (long)qt * QT + (lane >> 4) * 4) * S
                  + z * 256 + lt * 64 + (lane & 15) * 4;
  float s = 0.f;
#pragma unroll
  for (int rr = 0; rr < 4; ++rr) {
    const float4 a = *(const float4*)&mp[(long)rr * S];
    s += fabsf(a.x) + fabsf(a.y) + fabsf(a.z) + fabsf(a.w);
  }
  s += __shfl_xor(s, 1);
  s += __shfl_xor(s, 2);
  s += __shfl_xor(s, 4);
  s += __shfl_xor(s, 8);
  s += __shfl_xor(s, 16);
  s += __shfl_xor(s, 32);
  if (lane == 0 && !(s == 0.f))        // !(s==0) catches NaN too
    atomicOr(&fm[b * (S / QT) + qt], 1u << (z * 4 + lt));
}

// ---------- Kernel 0b: transpose+convert weights to bf16 Wt[n][k]; SCALE*log2e into Wq/Wqb --
__global__ __launch_bounds__(256) void wcvt_kernel(
    const float* __restrict__ Wq, const float* __restrict__ Wk, const float* __restrict__ Wv,
    const float* __restrict__ Wqb, const float* __restrict__ Wkb, const float* __restrict__ Wf,
    ushort_t* __restrict__ Wt)
{
  const float* Ws[6] = {Wq, Wk, Wv, Wqb, Wkb, Wf};
  const float scl[6] = {SCALEL, 1.f, 1.f, SCALEL, 1.f, 1.f};
  const int m = blockIdx.y;
  const int kb = blockIdx.x;           // 32-row slab of k
  const float* W = Ws[m];
  const float sc = scl[m];
  __shared__ float T[32 * 132];
  const int t = threadIdx.x;
#pragma unroll
  for (int u = 0; u < 4; ++u) {        // 32 rows x 32 float4
    const int idx = u * 256 + t;
    const int row = idx >> 5, c4 = idx & 31;
    const float4 v = *(const float4*)&W[(kb * 32 + row) * H + c4 * 4];
    *(float4*)&T[row * 132 + c4 * 4] = v;
  }
  __syncthreads();
#pragma unroll
  for (int u = 0; u < 16; ++u) {       // 128 n x 32 kk
    const int idx = u * 256 + t;
    const int n = idx >> 5, kk = idx & 31;
    Wt[m * (H * H) + n * H + kb * 32 + kk] = f2bf(T[kk * 132 + n] * sc);
  }
}

// ---------- Kernel 1: 5 projections via MFMA; 16-row blocks, single barrier ----------
// Q,K,Qb,Kb: [B][NH][S][HS] bf16 (Q/Qb pre-scaled by SCALE*log2e) ; V: [B][NH][HS][S] bf16
__global__ __launch_bounds__(256) void proj_kernel(
    const float* __restrict__ item, const float* __restrict__ beh,
    const ushort_t* __restrict__ Wt,
    const float* __restrict__ bq, const float* __restrict__ bk, const float* __restrict__ bv,
    const float* __restrict__ bqb, const float* __restrict__ bkb,
    ushort_t* __restrict__ Qo, ushort_t* __restrict__ Ko, ushort_t* __restrict__ Qbo,
    ushort_t* __restrict__ Kbo, ushort_t* __restrict__ Vto)
{
  __shared__ ushort_t Xi[16 * 136];
  __shared__ ushort_t Xb[16 * 136];
  __shared__ ushort_t Yb[5][16 * 136];
  const int t = threadIdx.x;
  const long r0 = (long)blockIdx.x * 16;
#pragma unroll
  for (int u = 0; u < 2; ++u) {        // 16 rows x 32 float4 per matrix (512 each)
    const int idx = u * 256 + t;
    const int row = idx >> 5, c4 = idx & 31;
    const float4 vi = *(const float4*)&item[(r0 + row) * H + c4 * 4];
    const float4 vb = *(const float4*)&beh[(r0 + row) * H + c4 * 4];
    unsigned long long pi = (unsigned long long)f2bf(vi.x) | ((unsigned long long)f2bf(vi.y) << 16)
        | ((unsigned long long)f2bf(vi.z) << 32) | ((unsigned long long)f2bf(vi.w) << 48);
    unsigned long long pb = (unsigned long long)f2bf(vb.x) | ((unsigned long long)f2bf(vb.y) << 16)
        | ((unsigned long long)f2bf(vb.z) << 32) | ((unsigned long long)f2bf(vb.w) << 48);
    *(unsigned long long*)&Xi[row * 136 + c4 * 4] = pi;
    *(unsigned long long*)&Xb[row * 136 + c4 * 4] = pb;
  }
  __syncthreads();

  const int w = t >> 6, l = t & 63, l15 = l & 15, quad = l >> 4;
  const int bb = (int)(r0 >> 11);
  const int s0 = (int)(r0 & (S - 1));
  const float* bias[5] = {bq, bk, bv, bqb, bkb};
  const float bscale[5] = {SCALEL, 1.f, 1.f, SCALEL, 1.f};

  bf16x8 afi[4], afb[4];
#pragma unroll
  for (int ks = 0; ks < 4; ++ks) {
    afi[ks] = *(const bf16x8*)&Xi[l15 * 136 + ks * 32 + quad * 8];
    afb[ks] = *(const bf16x8*)&Xb[l15 * 136 + ks * 32 + quad * 8];
  }

#pragma unroll
  for (int p = 0; p < 5; ++p) {
    f32x4 acc[2];
#pragma unroll
    for (int nt = 0; nt < 2; ++nt) {
      const float bcol = bias[p][w * 32 + nt * 16 + l15] * bscale[p];
      acc[nt] = (f32x4){bcol, bcol, bcol, bcol};
    }
    const ushort_t* Wp = Wt + p * (H * H);
    const bf16x8* af = (p < 3) ? afi : afb;
#pragma unroll
    for (int ks = 0; ks < 4; ++ks) {
      bf16x8 bfr[2];
#pragma unroll
      for (int nt = 0; nt < 2; ++nt)
        bfr[nt] = *(const bf16x8*)&Wp[(w * 32 + nt * 16 + l15) * H + ks * 32 + quad * 8];
#pragma unroll
      for (int nt = 0; nt < 2; ++nt)
        acc[nt] = mfma16(af[ks], bfr[nt], acc[nt]);
    }
#pragma unroll
    for (int nt = 0; nt < 2; ++nt)
#pragma unroll
      for (int r = 0; r < 4; ++r)
        Yb[p][(quad * 4 + r) * 136 + w * 32 + nt * 16 + l15] = f2bf(acc[nt][r]);
  }
  __syncthreads();
  // coalesced stores, all 5 matrices
  {
    const int row = t >> 4, cb = (t & 15) * 8;
    const int h = cb >> 5, dd = cb & 31;
    const long gidx = ((long)(bb * NH + h) * S + s0 + row) * HS + dd;
    ushort_t* dsts4[4] = {Qo, Ko, Qbo, Kbo};
    const int psrc[4] = {0, 1, 3, 4};
#pragma unroll
    for (int i = 0; i < 4; ++i)
      *(uint4*)&dsts4[i][gidx] = *(const uint4*)&Yb[psrc[i]][row * 136 + cb];
    const int d = t >> 1, sh = (t & 1) * 8;
    ushort_t tmp[8];
#pragma unroll
    for (int i = 0; i < 8; ++i) tmp[i] = Yb[2][(sh + i) * 136 + d];
    const long vidx = ((long)(bb * NH + (d >> 5)) * HS + (d & 31)) * S + s0 + sh;
    *(uint4*)&Vto[vidx] = *(const uint4*)&tmp[0];
  }
}

// ---------- Kernel 2: MFMA flash attention, split-K, flag-gated mask, ping-pong prefetch ----
__device__ __forceinline__ void attn_step(
    int k0, int kn, bool msknz,
    const bf16x8 (&kfc)[4], const bf16x8 (&kbfc)[4],
    bf16x8 (&kfn)[4], bf16x8 (&kbfn)[4],
    const bf16x8& qf, const bf16x8& qbf,
    const ushort_t* __restrict__ K, const ushort_t* __restrict__ Kb,
    const ushort_t* __restrict__ Vt,
    long hQ, long hV, const float* const (&mrow)[4],
    int l15, int quad, ushort_t* Pw,
    float (&lsum)[4], f32x4 (&O)[2])
{
  // V frags first so PV's wait never drains next-K loads
  bf16x8 vf[2][2];
#pragma unroll
  for (int dt = 0; dt < 2; ++dt)
#pragma unroll
    for (int ks = 0; ks < 2; ++ks)
      vf[dt][ks] = *(const bf16x8*)&Vt[hV + (long)(dt * 16 + l15) * S + k0 + ks * 32 + quad * 8];
  // prefetch next tile's K/Kb
#pragma unroll
  for (int nt = 0; nt < 4; ++nt) {
    kfn[nt]  = *(const bf16x8*)&K[hQ + (long)(kn + nt * 16 + l15) * HS + quad * 8];
    kbfn[nt] = *(const bf16x8*)&Kb[hQ + (long)(kn + nt * 16 + l15) * HS + quad * 8];
  }
  // score C-operand: mask*log2e only if tile flagged nonzero (wave-uniform branch)
  f32x4 sc[4];
  if (msknz) {
#pragma unroll
    for (int nt = 0; nt < 4; ++nt)
#pragma unroll
      for (int r = 0; r < 4; ++r)
        sc[nt][r] = mrow[r][k0 + nt * 16] * LOG2E;
  } else {
#pragma unroll
    for (int nt = 0; nt < 4; ++nt)
      sc[nt] = (f32x4){0.f, 0.f, 0.f, 0.f};
  }
  // scores (in log2 domain; Q pre-scaled by SCALE*log2e)
#pragma unroll
  for (int nt = 0; nt < 4; ++nt) {
    sc[nt] = mfma16(qbf, kbfc[nt], sc[nt]);
    sc[nt] = mfma16(qf, kfc[nt], sc[nt]);
  }
  // fixed-base softmax: p = 2^sc (raw v_exp_f32); per-lane partial sums
#pragma unroll
  for (int nt = 0; nt < 4; ++nt)
#pragma unroll
    for (int r = 0; r < 4; ++r)
      sc[nt][r] = __builtin_amdgcn_exp2f(sc[nt][r]);
#pragma unroll
  for (int r = 0; r < 4; ++r)
    lsum[r] += sc[0][r] + sc[1][r] + sc[2][r] + sc[3][r];
  // P -> bf16 by truncation (>>16): ~0.2% downward bias appears in O and lsum alike -> cancels
#pragma unroll
  for (int nt = 0; nt < 4; ++nt)
#pragma unroll
    for (int r = 0; r < 4; ++r)
      Pw[(quad * 4 + r) * 72 + nt * 16 + l15] =
          (ushort_t)(__float_as_uint(sc[nt][r]) >> 16);
  bf16x8 pf[2];
#pragma unroll
  for (int ks = 0; ks < 2; ++ks)
    pf[ks] = *(const bf16x8*)&Pw[l15 * 72 + ks * 32 + quad * 8];
#pragma unroll
  for (int dt = 0; dt < 2; ++dt)
#pragma unroll
    for (int ks = 0; ks < 2; ++ks)
      O[dt] = mfma16(pf[ks], vf[dt][ks], O[dt]);
}

__global__ __launch_bounds__(256, 8) void attn_kernel(
    const ushort_t* __restrict__ Q, const ushort_t* __restrict__ K,
    const ushort_t* __restrict__ Qb, const ushort_t* __restrict__ Kb,
    const ushort_t* __restrict__ Vt, const float* __restrict__ mask,
    const unsigned* __restrict__ fmg,
    ushort_t* __restrict__ PO, float* __restrict__ lsumP)
{
  __shared__ ushort_t Pb[NH][16 * 72];   // per-wave P scratch
  const int t = threadIdx.x;
  const int w = t >> 6;                  // head
  const int l15 = t & 15, quad = (t & 63) >> 4;
  const int q0 = blockIdx.x * QT;
  const int b = blockIdx.y;
  const int kz = blockIdx.z;             // split index
  const int kbase = kz * (S / KS);
  const long hQ = (long)(b * NH + w) * S * HS;
  const long hV = (long)(b * NH + w) * HS * S;

  const bf16x8 qf  = *(const bf16x8*)&Q[hQ + (long)(q0 + l15) * HS + quad * 8];
  const bf16x8 qbf = *(const bf16x8*)&Qb[hQ + (long)(q0 + l15) * HS + quad * 8];

  const unsigned fm = fmg[b * (S / QT) + blockIdx.x];

  const float* mrow[4];
#pragma unroll
  for (int r = 0; r < 4; ++r)
    mrow[r] = mask + ((long)b * S + q0 + quad * 4 + r) * S + l15;

  float lsum[4] = {0.f, 0.f, 0.f, 0.f};
  f32x4 O[2];
#pragma unroll
  for (int dt = 0; dt < 2; ++dt) O[dt] = (f32x4){0.f, 0.f, 0.f, 0.f};
  ushort_t* Pw = Pb[w];

  // ping-pong K/Kb fragment buffers
  bf16x8 kfA[4], kbfA[4], kfB[4], kbfB[4];
#pragma unroll
  for (int nt = 0; nt < 4; ++nt) {
    kfA[nt]  = *(const bf16x8*)&K[hQ + (long)(kbase + nt * 16 + l15) * HS + quad * 8];
    kbfA[nt] = *(const bf16x8*)&Kb[hQ + (long)(kbase + nt * 16 + l15) * HS + quad * 8];
  }

  for (int i = 0; i < SKT; i += 2) {
    const int k0 = kbase + i * KT;
    const int kn1 = k0 + KT;
    const int kn2 = (i + 2 < SKT) ? k0 + 2 * KT : kbase;       // clamped dummy on last pair
    attn_step(k0, kn1, (fm >> (kz * SKT + i)) & 1u, kfA, kbfA, kfB, kbfB,
              qf, qbf, K, Kb, Vt, hQ, hV, mrow, l15, quad, Pw, lsum, O);
    attn_step(kn1, kn2, (fm >> (kz * SKT + i + 1)) & 1u, kfB, kbfB, kfA, kbfA,
              qf, qbf, K, Kb, Vt, hQ, hV, mrow, l15, quad, Pw, lsum, O);
  }
  // one cross-lane reduction of row sums (16 k-lanes)
#pragma unroll
  for (int r = 0; r < 4; ++r) {
    float s = lsum[r];
    s += __shfl_xor(s, 1);
    s += __shfl_xor(s, 2);
    s += __shfl_xor(s, 4);
    s += __shfl_xor(s, 8);
    lsum[r] = s;
  }
  // epilogue: unnormalized partial O (bf16) + partial lsum (f32)
#pragma unroll
  for (int r = 0; r < 4; ++r) {
    const long row = (long)b * S + q0 + quad * 4 + r;
#pragma unroll
    for (int dt = 0; dt < 2; ++dt)
      PO[(long)kz * NE + row * H + w * 32 + dt * 16 + l15] = f2bf(O[dt][r]);
    if (l15 == 0)
      lsumP[((long)(kz * B + b) * NH + w) * S + q0 + quad * 4 + r] = lsum[r];
  }
}

// ---------- Kernel 2b: combine split-K partials -> normalized bf16 attn [B][S][H] ----------
__global__ __launch_bounds__(256) void comb_kernel(
    const ushort_t* __restrict__ PO, const float* __restrict__ lsumP,
    ushort_t* __restrict__ attn_out)
{
  const long idx8 = ((long)blockIdx.x * 256 + threadIdx.x) * 8;
  const int col = (int)(idx8 & (H - 1));
  const long row = idx8 >> 7;
  const int b = (int)(row >> 11);
  const int s = (int)(row & (S - 1));
  const int h = col >> 5;
  const float l = lsumP[((long)(0 * B + b) * NH + h) * S + s]
                + lsumP[((long)(1 * B + b) * NH + h) * S + s];
  const float inv = 1.f / l;
  const uint4 a0 = *(const uint4*)&PO[idx8];
  const uint4 a1 = *(const uint4*)&PO[(long)NE + idx8];
  uint4 res;
  const unsigned av0[4] = {a0.x, a0.y, a0.z, a0.w};
  const unsigned av1[4] = {a1.x, a1.y, a1.z, a1.w};
  unsigned rv[4];
#pragma unroll
  for (int i = 0; i < 4; ++i) {
    const float lo = (__uint_as_float(av0[i] << 16) + __uint_as_float(av1[i] << 16)) * inv;
    const float hi = (__uint_as_float(av0[i] & 0xFFFF0000u)
                    + __uint_as_float(av1[i] & 0xFFFF0000u)) * inv;
    rv[i] = (unsigned)f2bf(lo) | ((unsigned)f2bf(hi) << 16);
  }
  res.x = rv[0]; res.y = rv[1]; res.z = rv[2]; res.w = rv[3];
  *(uint4*)&attn_out[idx8] = res;
}

// ---------- Kernel 3: attn @ Wf + bias + residual + LayerNorm (MFMA), 16-row blocks ----------
__global__ __launch_bounds__(256) void out_kernel(
    const ushort_t* __restrict__ attn, const float* __restrict__ item,
    const ushort_t* __restrict__ Wft, const float* __restrict__ bf_,
    const float* __restrict__ lnw, const float* __restrict__ lnb,
    float* __restrict__ out)
{
  __shared__ ushort_t As[16 * 136];
  __shared__ float Ys[16 * 132];
  const int t = threadIdx.x;
  const long r0 = (long)blockIdx.x * 16;
  {
    const int row = t >> 4, c8 = t & 15;
    *(uint4*)&As[row * 136 + c8 * 8] = *(const uint4*)&attn[(r0 + row) * H + c8 * 8];
  }
  __syncthreads();
  const int w = t >> 6, l15 = t & 15, quad = (t & 63) >> 4;
  f32x4 acc[2];
#pragma unroll
  for (int nt = 0; nt < 2; ++nt) {
    const float bcol = bf_[w * 32 + nt * 16 + l15];
    acc[nt] = (f32x4){bcol, bcol, bcol, bcol};
  }
#pragma unroll
  for (int ks = 0; ks < 4; ++ks) {
    const bf16x8 a = *(const bf16x8*)&As[l15 * 136 + ks * 32 + quad * 8];
#pragma unroll
    for (int nt = 0; nt < 2; ++nt) {
      const bf16x8 bfr = *(const bf16x8*)&Wft[(w * 32 + nt * 16 + l15) * H + ks * 32 + quad * 8];
      acc[nt] = mfma16(a, bfr, acc[nt]);
    }
  }
#pragma unroll
  for (int nt = 0; nt < 2; ++nt)
#pragma unroll
    for (int r = 0; r < 4; ++r) {
      const int rl = quad * 4 + r;
      const int col = w * 32 + nt * 16 + l15;
      Ys[rl * 132 + col] = acc[nt][r] + item[(r0 + rl) * H + col];
    }
  __syncthreads();
  const int rl = t >> 4, ch = t & 15;
  float v[8];
#pragma unroll
  for (int g = 0; g < 2; ++g) {
    const float4 y = *(const float4*)&Ys[rl * 132 + ch * 8 + g * 4];
    v[g * 4 + 0] = y.x; v[g * 4 + 1] = y.y; v[g * 4 + 2] = y.z; v[g * 4 + 3] = y.w;
  }
  float s = 0.f;
#pragma unroll
  for (int i = 0; i < 8; ++i) s += v[i];
  s += __shfl_xor(s, 1);
  s += __shfl_xor(s, 2);
  s += __shfl_xor(s, 4);
  s += __shfl_xor(s, 8);
  const float u_ = s * (1.f / H);
  float s2 = 0.f;
#pragma unroll
  for (int i = 0; i < 8; ++i) { const float d = v[i] - u_; s2 += d * d; }
  s2 += __shfl_xor(s2, 1);
  s2 += __shfl_xor(s2, 2);
  s2 += __shfl_xor(s2, 4);
  s2 += __shfl_xor(s2, 8);
  const float rinv = rsqrtf(s2 * (1.f / H) + EPS);
#pragma unroll
  for (int g = 0; g < 2; ++g) {
    float4 o;
    const int col = ch * 8 + g * 4;
    o.x = lnw[col + 0] * ((v[g * 4 + 0] - u_) * rinv) + lnb[col + 0];
    o.y = lnw[col + 1] * ((v[g * 4 + 1] - u_) * rinv) + lnb[col + 1];
    o.z = lnw[col + 2] * ((v[g * 4 + 2] - u_) * rinv) + lnb[col + 2];
    o.w = lnw[col + 3] * ((v[g * 4 + 3] - u_) * rinv) + lnb[col + 3];
    *(float4*)&out[(r0 + rl) * H + col] = o;
  }
}

extern "C" void kernel_launch(void* const* d_in, const int* in_sizes, int n_in,
                              void* d_out, int out_size, void* d_ws, size_t ws_size,
                              hipStream_t stream) {
  const float* item = (const float*)d_in[0];
  const float* beh  = (const float*)d_in[1];
  const float* mask = (const float*)d_in[2];
  const float* Wq  = (const float*)d_in[3];  const float* bq  = (const float*)d_in[4];
  const float* Wk  = (const float*)d_in[5];  const float* bk  = (const float*)d_in[6];
  const float* Wv  = (const float*)d_in[7];  const float* bv  = (const float*)d_in[8];
  const float* Wqb = (const float*)d_in[9];  const float* bqb = (const float*)d_in[10];
  const float* Wkb = (const float*)d_in[11]; const float* bkb = (const float*)d_in[12];
  // d_in[13]/[14] = Wvb/bvb: dead code in the reference
  const float* Wf  = (const float*)d_in[15]; const float* bfv = (const float*)d_in[16];
  const float* lnw = (const float*)d_in[17]; const float* lnb = (const float*)d_in[18];
  float* out = (float*)d_out;

  ushort_t* ws = (ushort_t*)d_ws;
  ushort_t* Qw   = ws;
  ushort_t* Kw   = Qw + NE;
  ushort_t* Qbw  = Kw + NE;
  ushort_t* Kbw  = Qbw + NE;
  ushort_t* Vtw  = Kbw + NE;
  ushort_t* Attw = Vtw + NE;
  ushort_t* PO   = Attw + NE;                      // KS * NE bf16 partials
  ushort_t* Wt   = PO + (long)KS * NE;             // 6 * H*H bf16
  unsigned* fm   = (unsigned*)(Wt + 6 * H * H);    // B * (S/QT) uints
  float* lsumP   = (float*)(fm + B * (S / QT));    // KS * B * NH * S f32

  hipMemsetAsync(fm, 0, B * (S / QT) * sizeof(unsigned), stream);
  mflag_kernel<<<dim3(S / QT, B, 8), 256, 0, stream>>>(mask, fm);
  wcvt_kernel<<<dim3(4, 6), 256, 0, stream>>>(Wq, Wk, Wv, Wqb, Wkb, Wf, Wt);
  proj_kernel<<<dim3((B * S) / 16), 256, 0, stream>>>(
      item, beh, Wt, bq, bk, bv, bqb, bkb, Qw, Kw, Qbw, Kbw, Vtw);
  attn_kernel<<<dim3(S / QT, B, KS), 256, 0, stream>>>(
      Qw, Kw, Qbw, Kbw, Vtw, mask, fm, PO, lsumP);
  comb_kernel<<<dim3(NE / (256 * 8)), 256, 0, stream>>>(PO, lsumP, Attw);
  out_kernel<<<dim3((B * S) / 16), 256, 0, stream>>>(
      Attw, item, Wt + 5 * H * H, bfv, lnw, lnb, out);
}

// Round 8
// 395.873 us; speedup vs baseline: 2.0426x; 2.0426x over previous
//
#include <hip/hip_runtime.h>
#include <math.h>

typedef unsigned short ushort_t;
typedef __attribute__((ext_vector_type(8))) short bf16x8;
typedef __attribute__((ext_vector_type(4))) float f32x4;

namespace {
constexpr int B = 8, S = 2048, H = 128, NH = 4, HS = 32;
constexpr float EPS = 1e-8f;
constexpr float SCALE = 0.17677669529663687f;   // 1/sqrt(32)
constexpr float LOG2E = 1.4426950408889634f;
constexpr float SCALEL = SCALE * LOG2E;         // folded into Wq/Wqb/bq/bqb
constexpr int QT = 16, KT = 64;
constexpr int KS = 2;                            // split-K factor
constexpr int SKT = S / KS / KT;                 // 16 k-tiles per split
constexpr int NE = B * S * H;                    // 2,097,152 elements per tensor
}

__device__ __forceinline__ ushort_t f2bf(float f) {
  unsigned u = __float_as_uint(f);
  unsigned r = (u + 0x7FFFu + ((u >> 16) & 1u)) >> 16;  // RNE
  return (ushort_t)r;
}

__device__ __forceinline__ f32x4 mfma16(bf16x8 a, bf16x8 b, f32x4 c) {
  return __builtin_amdgcn_mfma_f32_16x16x32_bf16(a, b, c, 0, 0, 0);
}

// ---------- Kernel 0a: mask-nonzero tile bits, 8-way column split ----------
__global__ __launch_bounds__(256) void mflag_kernel(
    const float* __restrict__ mask, unsigned* __restrict__ fm)
{
  const int qt = blockIdx.x;
  const int b  = blockIdx.y;
  const int z  = blockIdx.z;           // 256-col chunk = 4 k-tiles
  const int t = threadIdx.x;
  const int lt = t >> 6;               // k-tile within chunk (0..3)
  const int lane = t & 63;
  const float* mp = mask + ((long)b * S + (long)qt * QT + (lane >> 4) * 4) * S
                  + z * 256 + lt * 64 + (lane & 15) * 4;
  float s = 0.f;
#pragma unroll
  for (int rr = 0; rr < 4; ++rr) {
    const float4 a = *(const float4*)&mp[(long)rr * S];
    s += fabsf(a.x) + fabsf(a.y) + fabsf(a.z) + fabsf(a.w);
  }
  s += __shfl_xor(s, 1);
  s += __shfl_xor(s, 2);
  s += __shfl_xor(s, 4);
  s += __shfl_xor(s, 8);
  s += __shfl_xor(s, 16);
  s += __shfl_xor(s, 32);
  if (lane == 0 && !(s == 0.f))        // !(s==0) catches NaN too
    atomicOr(&fm[b * (S / QT) + qt], 1u << (z * 4 + lt));
}

// ---------- Kernel 0b: transpose+convert weights to bf16 Wt[n][k]; SCALE*log2e into Wq/Wqb --
__global__ __launch_bounds__(256) void wcvt_kernel(
    const float* __restrict__ Wq, const float* __restrict__ Wk, const float* __restrict__ Wv,
    const float* __restrict__ Wqb, const float* __restrict__ Wkb, const float* __restrict__ Wf,
    ushort_t* __restrict__ Wt)
{
  const float* Ws[6] = {Wq, Wk, Wv, Wqb, Wkb, Wf};
  const float scl[6] = {SCALEL, 1.f, 1.f, SCALEL, 1.f, 1.f};
  const int m = blockIdx.y;
  const int kb = blockIdx.x;
  const float* W = Ws[m];
  const float sc = scl[m];
  __shared__ float T[32 * 132];
  const int t = threadIdx.x;
#pragma unroll
  for (int u = 0; u < 4; ++u) {
    const int idx = u * 256 + t;
    const int row = idx >> 5, c4 = idx & 31;
    const float4 v = *(const float4*)&W[(kb * 32 + row) * H + c4 * 4];
    *(float4*)&T[row * 132 + c4 * 4] = v;
  }
  __syncthreads();
#pragma unroll
  for (int u = 0; u < 16; ++u) {
    const int idx = u * 256 + t;
    const int n = idx >> 5, kk = idx & 31;
    Wt[m * (H * H) + n * H + kb * 32 + kk] = f2bf(T[kk * 132 + n] * sc);
  }
}

// ---------- Kernel 1: 5 projections via MFMA; V stored k-PERMUTED: Vp[d][64g + sig(k)] ----
// sig(k) = (k&15)*4 + (k>>4) within each 64-row group (matches attn's P/V slot order).
__global__ __launch_bounds__(256) void proj_kernel(
    const float* __restrict__ item, const float* __restrict__ beh,
    const ushort_t* __restrict__ Wt,
    const float* __restrict__ bq, const float* __restrict__ bk, const float* __restrict__ bv,
    const float* __restrict__ bqb, const float* __restrict__ bkb,
    ushort_t* __restrict__ Qo, ushort_t* __restrict__ Ko, ushort_t* __restrict__ Qbo,
    ushort_t* __restrict__ Kbo, ushort_t* __restrict__ Vto)
{
  __shared__ ushort_t Xi[16 * 136];
  __shared__ ushort_t Xb[16 * 136];
  __shared__ ushort_t Yb[5][16 * 136];
  const int t = threadIdx.x;
  const long r0 = (long)blockIdx.x * 16;
#pragma unroll
  for (int u = 0; u < 2; ++u) {
    const int idx = u * 256 + t;
    const int row = idx >> 5, c4 = idx & 31;
    const float4 vi = *(const float4*)&item[(r0 + row) * H + c4 * 4];
    const float4 vb = *(const float4*)&beh[(r0 + row) * H + c4 * 4];
    unsigned long long pi = (unsigned long long)f2bf(vi.x) | ((unsigned long long)f2bf(vi.y) << 16)
        | ((unsigned long long)f2bf(vi.z) << 32) | ((unsigned long long)f2bf(vi.w) << 48);
    unsigned long long pb = (unsigned long long)f2bf(vb.x) | ((unsigned long long)f2bf(vb.y) << 16)
        | ((unsigned long long)f2bf(vb.z) << 32) | ((unsigned long long)f2bf(vb.w) << 48);
    *(unsigned long long*)&Xi[row * 136 + c4 * 4] = pi;
    *(unsigned long long*)&Xb[row * 136 + c4 * 4] = pb;
  }
  __syncthreads();

  const int w = t >> 6, l = t & 63, l15 = l & 15, quad = l >> 4;
  const int bb = (int)(r0 >> 11);
  const int s0 = (int)(r0 & (S - 1));
  const float* bias[5] = {bq, bk, bv, bqb, bkb};
  const float bscale[5] = {SCALEL, 1.f, 1.f, SCALEL, 1.f};

  bf16x8 afi[4], afb[4];
#pragma unroll
  for (int ks = 0; ks < 4; ++ks) {
    afi[ks] = *(const bf16x8*)&Xi[l15 * 136 + ks * 32 + quad * 8];
    afb[ks] = *(const bf16x8*)&Xb[l15 * 136 + ks * 32 + quad * 8];
  }

#pragma unroll
  for (int p = 0; p < 5; ++p) {
    f32x4 acc[2];
#pragma unroll
    for (int nt = 0; nt < 2; ++nt) {
      const float bcol = bias[p][w * 32 + nt * 16 + l15] * bscale[p];
      acc[nt] = (f32x4){bcol, bcol, bcol, bcol};
    }
    const ushort_t* Wp = Wt + p * (H * H);
    const bf16x8* af = (p < 3) ? afi : afb;
#pragma unroll
    for (int ks = 0; ks < 4; ++ks) {
      bf16x8 bfr[2];
#pragma unroll
      for (int nt = 0; nt < 2; ++nt)
        bfr[nt] = *(const bf16x8*)&Wp[(w * 32 + nt * 16 + l15) * H + ks * 32 + quad * 8];
#pragma unroll
      for (int nt = 0; nt < 2; ++nt)
        acc[nt] = mfma16(af[ks], bfr[nt], acc[nt]);
    }
#pragma unroll
    for (int nt = 0; nt < 2; ++nt)
#pragma unroll
      for (int r = 0; r < 4; ++r)
        Yb[p][(quad * 4 + r) * 136 + w * 32 + nt * 16 + l15] = f2bf(acc[nt][r]);
  }
  __syncthreads();
  {
    // p = 0,1,3,4 : [b][h][s][d]; coalesced uint4
    const int row = t >> 4, cb = (t & 15) * 8;
    const int h = cb >> 5, dd = cb & 31;
    const long gidx = ((long)(bb * NH + h) * S + s0 + row) * HS + dd;
    ushort_t* dsts4[4] = {Qo, Ko, Qbo, Kbo};
    const int psrc[4] = {0, 1, 3, 4};
#pragma unroll
    for (int i = 0; i < 4; ++i)
      *(uint4*)&dsts4[i][gidx] = *(const uint4*)&Yb[psrc[i]][row * 136 + cb];
    // p = 2: Vp[b][h][d][ s64 + j*4 + nt ] = V[d][s0+j]   (sig permutation)
    const int d = t >> 1, sh = (t & 1) * 8;
    const int nt = (s0 >> 4) & 3;            // this block's 16 rows = one nt group
    const long vbase = ((long)(bb * NH + (d >> 5)) * HS + (d & 31)) * S + (s0 & ~63) + nt;
#pragma unroll
    for (int i = 0; i < 8; ++i)
      Vto[vbase + (long)(sh + i) * 4] = Yb[2][(sh + i) * 136 + d];
  }
}

// ---------- Kernel 2: MFMA flash attention, split-K, flag-gated mask, b64 P-writes ----------
__global__ __launch_bounds__(256, 4) void attn_kernel(
    const ushort_t* __restrict__ Q, const ushort_t* __restrict__ K,
    const ushort_t* __restrict__ Qb, const ushort_t* __restrict__ Kb,
    const ushort_t* __restrict__ Vt, const float* __restrict__ mask,
    const unsigned* __restrict__ fmg,
    ushort_t* __restrict__ PO, float* __restrict__ lsumP)
{
  __shared__ ushort_t Pb[NH][16 * 72];   // per-wave P scratch (sig-permuted cols)
  const int t = threadIdx.x;
  const int w = t >> 6;                  // head
  const int l15 = t & 15, quad = (t & 63) >> 4;
  const int q0 = blockIdx.x * QT;
  const int b = blockIdx.y;
  const int kz = blockIdx.z;             // split index
  const int kbase = kz * (S / KS);
  const long hQ = (long)(b * NH + w) * S * HS;
  const long hV = (long)(b * NH + w) * HS * S;

  const bf16x8 qf  = *(const bf16x8*)&Q[hQ + (long)(q0 + l15) * HS + quad * 8];
  const bf16x8 qbf = *(const bf16x8*)&Qb[hQ + (long)(q0 + l15) * HS + quad * 8];

  const unsigned fm = fmg[b * (S / QT) + blockIdx.x];

  const float* mrow[4];
#pragma unroll
  for (int r = 0; r < 4; ++r)
    mrow[r] = mask + ((long)b * S + q0 + quad * 4 + r) * S + l15;

  float lsum[4] = {0.f, 0.f, 0.f, 0.f};
  f32x4 O[2];
#pragma unroll
  for (int dt = 0; dt < 2; ++dt) O[dt] = (f32x4){0.f, 0.f, 0.f, 0.f};
  ushort_t* Pw = Pb[w];

  for (int i = 0; i < SKT; ++i) {
    const int k0 = kbase + i * KT;
    // 12 independent loads (K/Kb B-frags; V B-frags from sig-permuted Vp)
    bf16x8 kf[4], kbf[4], vf[2][2];
#pragma unroll
    for (int nt = 0; nt < 4; ++nt) {
      kf[nt]  = *(const bf16x8*)&K[hQ + (long)(k0 + nt * 16 + l15) * HS + quad * 8];
      kbf[nt] = *(const bf16x8*)&Kb[hQ + (long)(k0 + nt * 16 + l15) * HS + quad * 8];
    }
#pragma unroll
    for (int dt = 0; dt < 2; ++dt)
#pragma unroll
      for (int ks = 0; ks < 2; ++ks)
        vf[dt][ks] = *(const bf16x8*)&Vt[hV + (long)(dt * 16 + l15) * S + k0 + ks * 32 + quad * 8];
    // score C-operand: mask*log2e only on flagged tiles (wave-uniform branch)
    f32x4 sc[4];
    if ((fm >> (kz * SKT + i)) & 1u) {
#pragma unroll
      for (int nt = 0; nt < 4; ++nt)
#pragma unroll
        for (int r = 0; r < 4; ++r)
          sc[nt][r] = mrow[r][k0 + nt * 16] * LOG2E;
    } else {
#pragma unroll
      for (int nt = 0; nt < 4; ++nt)
        sc[nt] = (f32x4){0.f, 0.f, 0.f, 0.f};
    }
    // scores (log2 domain; Q pre-scaled by SCALE*log2e)
#pragma unroll
    for (int nt = 0; nt < 4; ++nt) {
      sc[nt] = mfma16(qbf, kbf[nt], sc[nt]);
      sc[nt] = mfma16(qf, kf[nt], sc[nt]);
    }
    // fixed-base softmax: p = 2^sc ; per-lane partial sums
#pragma unroll
    for (int nt = 0; nt < 4; ++nt)
#pragma unroll
      for (int r = 0; r < 4; ++r)
        sc[nt][r] = __builtin_amdgcn_exp2f(sc[nt][r]);
#pragma unroll
    for (int r = 0; r < 4; ++r)
      lsum[r] += sc[0][r] + sc[1][r] + sc[2][r] + sc[3][r];
    // P -> LDS: sig-permuted col = l15*4 + nt  => 4 contiguous ushorts = ONE b64 per row
#pragma unroll
    for (int r = 0; r < 4; ++r) {
      const unsigned long long pk =
            (unsigned long long)(__float_as_uint(sc[0][r]) >> 16)
          | ((unsigned long long)(__float_as_uint(sc[1][r]) >> 16) << 16)
          | ((unsigned long long)(__float_as_uint(sc[2][r]) >> 16) << 32)
          | ((unsigned long long)(__float_as_uint(sc[3][r]) >> 16) << 48);
      *(unsigned long long*)&Pw[(quad * 4 + r) * 72 + l15 * 4] = pk;
    }
    // P A-frags (slot m = ks*32+quad*8+j matches Vp rows) + PV
    bf16x8 pf[2];
#pragma unroll
    for (int ks = 0; ks < 2; ++ks)
      pf[ks] = *(const bf16x8*)&Pw[l15 * 72 + ks * 32 + quad * 8];
#pragma unroll
    for (int dt = 0; dt < 2; ++dt)
#pragma unroll
      for (int ks = 0; ks < 2; ++ks)
        O[dt] = mfma16(pf[ks], vf[dt][ks], O[dt]);
  }
  // one cross-lane reduction of row sums (16 k-lanes)
#pragma unroll
  for (int r = 0; r < 4; ++r) {
    float s = lsum[r];
    s += __shfl_xor(s, 1);
    s += __shfl_xor(s, 2);
    s += __shfl_xor(s, 4);
    s += __shfl_xor(s, 8);
    lsum[r] = s;
  }
  // epilogue: unnormalized partial O (bf16) + partial lsum (f32)
#pragma unroll
  for (int r = 0; r < 4; ++r) {
    const long row = (long)b * S + q0 + quad * 4 + r;
#pragma unroll
    for (int dt = 0; dt < 2; ++dt)
      PO[(long)kz * NE + row * H + w * 32 + dt * 16 + l15] = f2bf(O[dt][r]);
    if (l15 == 0)
      lsumP[((long)(kz * B + b) * NH + w) * S + q0 + quad * 4 + r] = lsum[r];
  }
}

// ---------- Kernel 3: combine split-K + attn @ Wf + bias + residual + LayerNorm ----------
__global__ __launch_bounds__(256) void out_kernel(
    const ushort_t* __restrict__ PO, const float* __restrict__ lsumP,
    const float* __restrict__ item,
    const ushort_t* __restrict__ Wft, const float* __restrict__ bf_,
    const float* __restrict__ lnw, const float* __restrict__ lnb,
    float* __restrict__ out)
{
  __shared__ ushort_t As[16 * 136];
  __shared__ float Ys[16 * 132];
  const int t = threadIdx.x;
  const long r0 = (long)blockIdx.x * 16;
  {
    // fused split-K combine: As = (PO0 + PO1) / (l0 + l1), bf16
    const int row = t >> 4, c8 = t & 15;
    const long grow = r0 + row;
    const int b = (int)(grow >> 11);
    const int s = (int)(grow & (S - 1));
    const int h = c8 >> 2;
    const float l = lsumP[((long)(0 * B + b) * NH + h) * S + s]
                  + lsumP[((long)(1 * B + b) * NH + h) * S + s];
    const float inv = 1.f / l;
    const long gi = grow * H + c8 * 8;
    const uint4 a0 = *(const uint4*)&PO[gi];
    const uint4 a1 = *(const uint4*)&PO[(long)NE + gi];
    const unsigned av0[4] = {a0.x, a0.y, a0.z, a0.w};
    const unsigned av1[4] = {a1.x, a1.y, a1.z, a1.w};
    unsigned rv[4];
#pragma unroll
    for (int i = 0; i < 4; ++i) {
      const float lo = (__uint_as_float(av0[i] << 16) + __uint_as_float(av1[i] << 16)) * inv;
      const float hi = (__uint_as_float(av0[i] & 0xFFFF0000u)
                      + __uint_as_float(av1[i] & 0xFFFF0000u)) * inv;
      rv[i] = (unsigned)f2bf(lo) | ((unsigned)f2bf(hi) << 16);
    }
    uint4 res; res.x = rv[0]; res.y = rv[1]; res.z = rv[2]; res.w = rv[3];
    *(uint4*)&As[row * 136 + c8 * 8] = res;
  }
  __syncthreads();
  const int w = t >> 6, l15 = t & 15, quad = (t & 63) >> 4;
  f32x4 acc[2];
#pragma unroll
  for (int nt = 0; nt < 2; ++nt) {
    const float bcol = bf_[w * 32 + nt * 16 + l15];
    acc[nt] = (f32x4){bcol, bcol, bcol, bcol};
  }
#pragma unroll
  for (int ks = 0; ks < 4; ++ks) {
    const bf16x8 a = *(const bf16x8*)&As[l15 * 136 + ks * 32 + quad * 8];
#pragma unroll
    for (int nt = 0; nt < 2; ++nt) {
      const bf16x8 bfr = *(const bf16x8*)&Wft[(w * 32 + nt * 16 + l15) * H + ks * 32 + quad * 8];
      acc[nt] = mfma16(a, bfr, acc[nt]);
    }
  }
#pragma unroll
  for (int nt = 0; nt < 2; ++nt)
#pragma unroll
    for (int r = 0; r < 4; ++r) {
      const int rl = quad * 4 + r;
      const int col = w * 32 + nt * 16 + l15;
      Ys[rl * 132 + col] = acc[nt][r] + item[(r0 + rl) * H + col];
    }
  __syncthreads();
  const int rl = t >> 4, ch = t & 15;
  float v[8];
#pragma unroll
  for (int g = 0; g < 2; ++g) {
    const float4 y = *(const float4*)&Ys[rl * 132 + ch * 8 + g * 4];
    v[g * 4 + 0] = y.x; v[g * 4 + 1] = y.y; v[g * 4 + 2] = y.z; v[g * 4 + 3] = y.w;
  }
  float s = 0.f;
#pragma unroll
  for (int i = 0; i < 8; ++i) s += v[i];
  s += __shfl_xor(s, 1);
  s += __shfl_xor(s, 2);
  s += __shfl_xor(s, 4);
  s += __shfl_xor(s, 8);
  const float u_ = s * (1.f / H);
  float s2 = 0.f;
#pragma unroll
  for (int i = 0; i < 8; ++i) { const float d = v[i] - u_; s2 += d * d; }
  s2 += __shfl_xor(s2, 1);
  s2 += __shfl_xor(s2, 2);
  s2 += __shfl_xor(s2, 4);
  s2 += __shfl_xor(s2, 8);
  const float rinv = rsqrtf(s2 * (1.f / H) + EPS);
#pragma unroll
  for (int g = 0; g < 2; ++g) {
    float4 o;
    const int col = ch * 8 + g * 4;
    o.x = lnw[col + 0] * ((v[g * 4 + 0] - u_) * rinv) + lnb[col + 0];
    o.y = lnw[col + 1] * ((v[g * 4 + 1] - u_) * rinv) + lnb[col + 1];
    o.z = lnw[col + 2] * ((v[g * 4 + 2] - u_) * rinv) + lnb[col + 2];
    o.w = lnw[col + 3] * ((v[g * 4 + 3] - u_) * rinv) + lnb[col + 3];
    *(float4*)&out[(r0 + rl) * H + col] = o;
  }
}

extern "C" void kernel_launch(void* const* d_in, const int* in_sizes, int n_in,
                              void* d_out, int out_size, void* d_ws, size_t ws_size,
                              hipStream_t stream) {
  const float* item = (const float*)d_in[0];
  const float* beh  = (const float*)d_in[1];
  const float* mask = (const float*)d_in[2];
  const float* Wq  = (const float*)d_in[3];  const float* bq  = (const float*)d_in[4];
  const float* Wk  = (const float*)d_in[5];  const float* bk  = (const float*)d_in[6];
  const float* Wv  = (const float*)d_in[7];  const float* bv  = (const float*)d_in[8];
  const float* Wqb = (const float*)d_in[9];  const float* bqb = (const float*)d_in[10];
  const float* Wkb = (const float*)d_in[11]; const float* bkb = (const float*)d_in[12];
  // d_in[13]/[14] = Wvb/bvb: dead code in the reference
  const float* Wf  = (const float*)d_in[15]; const float* bfv = (const float*)d_in[16];
  const float* lnw = (const float*)d_in[17]; const float* lnb = (const float*)d_in[18];
  float* out = (float*)d_out;

  ushort_t* ws = (ushort_t*)d_ws;
  ushort_t* Qw   = ws;
  ushort_t* Kw   = Qw + NE;
  ushort_t* Qbw  = Kw + NE;
  ushort_t* Kbw  = Qbw + NE;
  ushort_t* Vtw  = Kbw + NE;
  ushort_t* PO   = Vtw + NE;                       // KS * NE bf16 partials
  ushort_t* Wt   = PO + (long)KS * NE;             // 6 * H*H bf16
  unsigned* fm   = (unsigned*)(Wt + 6 * H * H);    // B * (S/QT) uints
  float* lsumP   = (float*)(fm + B * (S / QT));    // KS * B * NH * S f32

  hipMemsetAsync(fm, 0, B * (S / QT) * sizeof(unsigned), stream);
  mflag_kernel<<<dim3(S / QT, B, 8), 256, 0, stream>>>(mask, fm);
  wcvt_kernel<<<dim3(4, 6), 256, 0, stream>>>(Wq, Wk, Wv, Wqb, Wkb, Wf, Wt);
  proj_kernel<<<dim3((B * S) / 16), 256, 0, stream>>>(
      item, beh, Wt, bq, bk, bv, bqb, bkb, Qw, Kw, Qbw, Kbw, Vtw);
  attn_kernel<<<dim3(S / QT, B, KS), 256, 0, stream>>>(
      Qw, Kw, Qbw, Kbw, Vtw, mask, fm, PO, lsumP);
  out_kernel<<<dim3((B * S) / 16), 256, 0, stream>>>(
      PO, lsumP, item, Wt + 5 * H * H, bfv, lnw, lnb, out);
}